// Round 1
// baseline (3654.099 us; speedup 1.0000x reference)
//
#include <hip/hip_runtime.h>
#include <hip/hip_bf16.h>

#define B_SZ 8
#define S_SZ 2048
#define D_DIM 1024
#define LR 0.01f

typedef __attribute__((ext_vector_type(8))) short short8;
typedef __attribute__((ext_vector_type(4))) float float4v;

static __device__ __forceinline__ unsigned short f2bf(float x) {
    union { float f; unsigned u; } un; un.f = x;
    unsigned r = un.u + 0x7fffu + ((un.u >> 16) & 1u);   // RNE
    return (unsigned short)(r >> 16);
}
static __device__ __forceinline__ float bf2f(unsigned short x) {
    union { float f; unsigned u; } un; un.u = ((unsigned)x) << 16;
    return un.f;
}

// ---------------------------------------------------------------------------
// Phase 1: C[z][m][n] = sum_k A[m][k] * Theta_z[n][k], output bf16.
// 64x64 tile, BK=32, 4 waves, MFMA 16x16x32 bf16. fp32->bf16 in staging.
// ---------------------------------------------------------------------------
__global__ __launch_bounds__(256) void proj_gemm(
    const float* __restrict__ A,
    const float* __restrict__ T0, const float* __restrict__ T1,
    const float* __restrict__ T2,
    unsigned short* __restrict__ out)
{
    const float* Bt = (blockIdx.z == 0) ? T0 : (blockIdx.z == 1 ? T1 : T2);
    unsigned short* C = out + (size_t)blockIdx.z * (size_t)(16384) * 1024;

    __shared__ unsigned short As[64][40];   // +8 pad: 80B row stride, 16B aligned
    __shared__ unsigned short Bs[64][40];

    const int tid  = threadIdx.x;
    const int lane = tid & 63;
    const int wave = tid >> 6;
    const int m0 = blockIdx.x * 64;
    const int n0 = blockIdx.y * 64;
    const int srow = tid >> 2;          // 0..63
    const int sseg = (tid & 3) * 8;     // 0,8,16,24
    const int mrow = lane & 15;
    const int quad = lane >> 4;

    float4v acc[4];
#pragma unroll
    for (int i = 0; i < 4; ++i) acc[i] = (float4v){0.f, 0.f, 0.f, 0.f};

    const float* apBase = A  + (size_t)(m0 + srow) * 1024 + sseg;
    const float* bpBase = Bt + (size_t)(n0 + srow) * 1024 + sseg;

    for (int kt = 0; kt < 1024; kt += 32) {
        const float4v* ap4 = (const float4v*)(apBase + kt);
        const float4v* bp4 = (const float4v*)(bpBase + kt);
        float4v av0 = ap4[0], av1 = ap4[1];
        float4v bv0 = bp4[0], bv1 = bp4[1];

        __syncthreads();   // previous iteration's fragment reads done
        short8 apk, bpk;
#pragma unroll
        for (int i = 0; i < 4; ++i) {
            apk[i]     = (short)f2bf(av0[i]);
            apk[i + 4] = (short)f2bf(av1[i]);
            bpk[i]     = (short)f2bf(bv0[i]);
            bpk[i + 4] = (short)f2bf(bv1[i]);
        }
        *(short8*)&As[srow][sseg] = apk;
        *(short8*)&Bs[srow][sseg] = bpk;
        __syncthreads();

        short8 af = *(const short8*)&As[16 * wave + mrow][quad * 8];
#pragma unroll
        for (int nb = 0; nb < 4; ++nb) {
            short8 bfr = *(const short8*)&Bs[16 * nb + mrow][quad * 8];
            acc[nb] = __builtin_amdgcn_mfma_f32_16x16x32_bf16(af, bfr, acc[nb], 0, 0, 0);
        }
    }

    // C/D layout: col = lane&15, row = (lane>>4)*4 + reg  [verified m89/m91]
#pragma unroll
    for (int nb = 0; nb < 4; ++nb) {
#pragma unroll
        for (int r = 0; r < 4; ++r) {
            int grow = m0 + 16 * wave + quad * 4 + r;
            int gcol = n0 + 16 * nb + mrow;
            C[(size_t)grow * 1024 + gcol] = f2bf(acc[nb][r]);
        }
    }
}

// ---------------------------------------------------------------------------
// Phase 2: row-parallel TTT scan. One wave owns 4 rows of W (fp32, registers,
// j strided by 64 across lanes, 16 j per lane). 512 blocks x 256 thr.
// ---------------------------------------------------------------------------
__global__ __launch_bounds__(256) void ttt_scan(
    const unsigned short* __restrict__ Kv,
    const unsigned short* __restrict__ Vv,
    const unsigned short* __restrict__ Qv,
    const float* __restrict__ W0,
    const float* __restrict__ b0,
    float* __restrict__ out)
{
    const int lane  = threadIdx.x & 63;
    const int wave  = threadIdx.x >> 6;
    const int batch = blockIdx.y;
    const int row0  = blockIdx.x * 16 + wave * 4;

    float w[4][16];
#pragma unroll
    for (int r = 0; r < 4; ++r)
#pragma unroll
        for (int jj = 0; jj < 16; ++jj)
            w[r][jj] = W0[(size_t)(row0 + r) * 1024 + lane + 64 * jj];

    float bias[4];
#pragma unroll
    for (int r = 0; r < 4; ++r) bias[r] = b0[row0 + r];

    const unsigned short* Kb = Kv + (size_t)batch * S_SZ * 1024;
    const unsigned short* Vb = Vv + (size_t)batch * S_SZ * 1024;
    const unsigned short* Qb = Qv + (size_t)batch * S_SZ * 1024;
    float* ob = out + (size_t)batch * S_SZ * 1024;

    const float gscale = 2.0f / 1024.0f;

    for (int s = 0; s < S_SZ; ++s) {
        const unsigned short* kp = Kb + (size_t)s * 1024 + lane;
        const unsigned short* qp = Qb + (size_t)s * 1024 + lane;
        float kv[16], qv[16];
#pragma unroll
        for (int jj = 0; jj < 16; ++jj) kv[jj] = bf2f(kp[64 * jj]);
#pragma unroll
        for (int jj = 0; jj < 16; ++jj) qv[jj] = bf2f(qp[64 * jj]);

        float g[4];
#pragma unroll
        for (int r = 0; r < 4; ++r) {
            float p = 0.f;
#pragma unroll
            for (int jj = 0; jj < 16; ++jj) p = fmaf(w[r][jj], kv[jj], p);
#pragma unroll
            for (int off = 32; off > 0; off >>= 1) p += __shfl_xor(p, off, 64);
            float vr = bf2f(Vb[(size_t)s * 1024 + row0 + r]);
            g[r] = gscale * (p + bias[r] - vr);
        }

        float oval = 0.f;
#pragma unroll
        for (int r = 0; r < 4; ++r) {
            const float nl = -LR * g[r];
            float p = 0.f;
#pragma unroll
            for (int jj = 0; jj < 16; ++jj) {
                w[r][jj] = fmaf(nl, kv[jj], w[r][jj]);   // W -= LR*g*k
                p = fmaf(w[r][jj], qv[jj], p);           // (new W) @ q
            }
#pragma unroll
            for (int off = 32; off > 0; off >>= 1) p += __shfl_xor(p, off, 64);
            bias[r] += nl;                               // b -= LR*g
            float o = p + bias[r];
            if (lane == r) oval = o;
        }
        if (lane < 4) ob[(size_t)s * 1024 + row0 + lane] = oval;
    }
}

// ---------------------------------------------------------------------------
extern "C" void kernel_launch(void* const* d_in, const int* in_sizes, int n_in,
                              void* d_out, int out_size, void* d_ws, size_t ws_size,
                              hipStream_t stream) {
    (void)in_sizes; (void)n_in; (void)out_size; (void)ws_size;
    const float* in_seq = (const float*)d_in[0];
    const float* thK    = (const float*)d_in[1];
    const float* thV    = (const float*)d_in[2];
    const float* thQ    = (const float*)d_in[3];
    const float* W0     = (const float*)d_in[4];
    const float* b0     = (const float*)d_in[5];
    float* out = (float*)d_out;

    unsigned short* kvq = (unsigned short*)d_ws;          // [3][16384][1024] bf16
    unsigned short* Kp = kvq;
    unsigned short* Vp = kvq + (size_t)16384 * 1024;
    unsigned short* Qp = kvq + (size_t)2 * 16384 * 1024;

    dim3 g1(16384 / 64, 1024 / 64, 3);
    proj_gemm<<<g1, 256, 0, stream>>>(in_seq, thK, thV, thQ, kvq);

    dim3 g2(64, B_SZ);
    ttt_scan<<<g2, 256, 0, stream>>>(Kp, Vp, Qp, W0, b0, out);
}

// Round 2
// 1394.167 us; speedup vs baseline: 2.6210x; 2.6210x over previous
//
#include <hip/hip_runtime.h>
#include <hip/hip_bf16.h>

#define LR 0.01f

typedef __attribute__((ext_vector_type(8))) short short8;
typedef __attribute__((ext_vector_type(4))) float float4v;
typedef __attribute__((ext_vector_type(4))) unsigned short ushort4v;

static __device__ __forceinline__ unsigned short f2bf(float x) {
    union { float f; unsigned u; } un; un.f = x;
    unsigned r = un.u + 0x7fffu + ((un.u >> 16) & 1u);   // RNE
    return (unsigned short)(r >> 16);
}
static __device__ __forceinline__ float bf2f(unsigned short x) {
    union { float f; unsigned u; } un; un.u = ((unsigned)x) << 16;
    return un.f;
}

// ---------------------------------------------------------------------------
// Phase 1: K/V/Q projections, bf16 out. Also writes Kt = -LR * K^T  [b][j][s].
// ---------------------------------------------------------------------------
__global__ __launch_bounds__(256) void proj_gemm(
    const float* __restrict__ A,
    const float* __restrict__ T0, const float* __restrict__ T1,
    const float* __restrict__ T2,
    unsigned short* __restrict__ out,
    unsigned short* __restrict__ ktw)
{
    const float* Bt = (blockIdx.z == 0) ? T0 : (blockIdx.z == 1 ? T1 : T2);
    unsigned short* C = out + (size_t)blockIdx.z * (size_t)16384 * 1024;

    __shared__ unsigned short As[64][40];
    __shared__ unsigned short Bs[64][40];

    const int tid  = threadIdx.x;
    const int lane = tid & 63;
    const int wave = tid >> 6;
    const int m0 = blockIdx.x * 64;
    const int n0 = blockIdx.y * 64;
    const int srow = tid >> 2;
    const int sseg = (tid & 3) * 8;
    const int mrow = lane & 15;
    const int quad = lane >> 4;

    float4v acc[4];
#pragma unroll
    for (int i = 0; i < 4; ++i) acc[i] = (float4v){0.f, 0.f, 0.f, 0.f};

    const float* apBase = A  + (size_t)(m0 + srow) * 1024 + sseg;
    const float* bpBase = Bt + (size_t)(n0 + srow) * 1024 + sseg;

    for (int kt = 0; kt < 1024; kt += 32) {
        const float4v* ap4 = (const float4v*)(apBase + kt);
        const float4v* bp4 = (const float4v*)(bpBase + kt);
        float4v av0 = ap4[0], av1 = ap4[1];
        float4v bv0 = bp4[0], bv1 = bp4[1];

        __syncthreads();
        short8 apk, bpk;
#pragma unroll
        for (int i = 0; i < 4; ++i) {
            apk[i]     = (short)f2bf(av0[i]);
            apk[i + 4] = (short)f2bf(av1[i]);
            bpk[i]     = (short)f2bf(bv0[i]);
            bpk[i + 4] = (short)f2bf(bv1[i]);
        }
        *(short8*)&As[srow][sseg] = apk;
        *(short8*)&Bs[srow][sseg] = bpk;
        __syncthreads();

        short8 af = *(const short8*)&As[16 * wave + mrow][quad * 8];
#pragma unroll
        for (int nb = 0; nb < 4; ++nb) {
            short8 bfr = *(const short8*)&Bs[16 * nb + mrow][quad * 8];
            acc[nb] = __builtin_amdgcn_mfma_f32_16x16x32_bf16(af, bfr, acc[nb], 0, 0, 0);
        }
    }

    const int batch = m0 >> 11;
    const int s0    = m0 & 2047;
#pragma unroll
    for (int nb = 0; nb < 4; ++nb) {
#pragma unroll
        for (int r = 0; r < 4; ++r) {
            int tl = 16 * wave + quad * 4 + r;     // token-local
            int jl = 16 * nb + mrow;               // dim-local
            C[(size_t)(m0 + tl) * 1024 + (n0 + jl)] = f2bf(acc[nb][r]);
            if (blockIdx.z == 0) {
                ktw[(size_t)batch * 2097152 + (size_t)(n0 + jl) * 2048 + s0 + tl] =
                    f2bf(-LR * acc[nb][r]);
            }
        }
    }
}

// ---------------------------------------------------------------------------
// Phase 2: per (batch, chunk): Linv = (I+L)^-1 via Neumann (I - L + L^2 - L^3),
// Mp = -LR * tril(Q K^T + 1). L = (2LR/d)*strict_tril(K K^T + 1).
// ---------------------------------------------------------------------------
__global__ __launch_bounds__(256) void precomp(
    const unsigned short* __restrict__ K,
    const unsigned short* __restrict__ Q,
    unsigned short* __restrict__ LinvG,
    unsigned short* __restrict__ MpG)
{
    __shared__ float Skk[64][68];
    __shared__ float Sqk[64][68];
    __shared__ unsigned short Lb[64][72];
    __shared__ unsigned short Xa[64][72];   // holds X^T (bf16)

    const int tid = threadIdx.x;
    const int lane = tid & 63;
    const int w = tid >> 6;
    const int lm = lane & 15;
    const int quad = lane >> 4;
    const int batch = blockIdx.x >> 5;
    const int c = blockIdx.x & 31;
    const size_t blk = (size_t)batch * 32 + c;

    float4v kk[4], qk[4];
#pragma unroll
    for (int i = 0; i < 4; ++i) { kk[i] = (float4v){0,0,0,0}; qk[i] = (float4v){0,0,0,0}; }

    const size_t tokA = (size_t)batch * 2048 + c * 64 + w * 16 + lm;
#pragma unroll 4
    for (int ks = 0; ks < 32; ++ks) {
        short8 aK = *(const short8*)(K + tokA * 1024 + ks * 32 + quad * 8);
        short8 aQ = *(const short8*)(Q + tokA * 1024 + ks * 32 + quad * 8);
#pragma unroll
        for (int nb = 0; nb < 4; ++nb) {
            size_t tokB = (size_t)batch * 2048 + c * 64 + nb * 16 + lm;
            short8 bK = *(const short8*)(K + tokB * 1024 + ks * 32 + quad * 8);
            kk[nb] = __builtin_amdgcn_mfma_f32_16x16x32_bf16(aK, bK, kk[nb], 0, 0, 0);
            qk[nb] = __builtin_amdgcn_mfma_f32_16x16x32_bf16(aQ, bK, qk[nb], 0, 0, 0);
        }
    }
#pragma unroll
    for (int nb = 0; nb < 4; ++nb)
#pragma unroll
        for (int r = 0; r < 4; ++r) {
            Skk[w * 16 + quad * 4 + r][nb * 16 + lm] = kk[nb][r];
            Sqk[w * 16 + quad * 4 + r][nb * 16 + lm] = qk[nb][r];
        }
    __syncthreads();

    const float c1 = 2.0f * LR / 1024.0f;
#pragma unroll
    for (int e = 0; e < 16; ++e) {
        int idx = tid * 16 + e;
        int t = idx >> 6, i = idx & 63;
        float a = (i < t) ? c1 * (Skk[t][i] + 1.0f) : 0.0f;
        Lb[t][i] = f2bf(a);
        Xa[i][t] = f2bf(((i == t) ? 1.0f : 0.0f) - a);
        float mq = (i <= t) ? -LR * (Sqk[t][i] + 1.0f) : 0.0f;
        MpG[blk * 4096 + (size_t)t * 64 + i] = f2bf(mq);
    }
    __syncthreads();

    // iteration 1: P = L * X0, X1 = I - P  (write X1^T into Xa)
    short8 afL0 = *(const short8*)&Lb[w * 16 + lm][quad * 8];
    short8 afL1 = *(const short8*)&Lb[w * 16 + lm][32 + quad * 8];
    float4v p[4];
#pragma unroll
    for (int nb = 0; nb < 4; ++nb) {
        p[nb] = (float4v){0,0,0,0};
        short8 b0f = *(const short8*)&Xa[nb * 16 + lm][quad * 8];
        short8 b1f = *(const short8*)&Xa[nb * 16 + lm][32 + quad * 8];
        p[nb] = __builtin_amdgcn_mfma_f32_16x16x32_bf16(afL0, b0f, p[nb], 0, 0, 0);
        p[nb] = __builtin_amdgcn_mfma_f32_16x16x32_bf16(afL1, b1f, p[nb], 0, 0, 0);
    }
    __syncthreads();
#pragma unroll
    for (int nb = 0; nb < 4; ++nb)
#pragma unroll
        for (int r = 0; r < 4; ++r) {
            int ii = nb * 16 + lm, tt = w * 16 + quad * 4 + r;
            Xa[ii][tt] = f2bf(((ii == tt) ? 1.0f : 0.0f) - p[nb][r]);
        }
    __syncthreads();

    // iteration 2: P2 = L * X1, Linv = I - P2  (write global, row-major)
#pragma unroll
    for (int nb = 0; nb < 4; ++nb) {
        p[nb] = (float4v){0,0,0,0};
        short8 b0f = *(const short8*)&Xa[nb * 16 + lm][quad * 8];
        short8 b1f = *(const short8*)&Xa[nb * 16 + lm][32 + quad * 8];
        p[nb] = __builtin_amdgcn_mfma_f32_16x16x32_bf16(afL0, b0f, p[nb], 0, 0, 0);
        p[nb] = __builtin_amdgcn_mfma_f32_16x16x32_bf16(afL1, b1f, p[nb], 0, 0, 0);
    }
#pragma unroll
    for (int nb = 0; nb < 4; ++nb)
#pragma unroll
        for (int r = 0; r < 4; ++r) {
            int ii = nb * 16 + lm, tt = w * 16 + quad * 4 + r;
            LinvG[blk * 4096 + (size_t)tt * 64 + ii] =
                f2bf(((ii == tt) ? 1.0f : 0.0f) - p[nb][r]);
        }
}

// ---------------------------------------------------------------------------
// Phase 3: chunked TTT. 256 blocks = 8 batches x 32 row-slabs. W slab (32x1024)
// lives in MFMA accumulator registers (fp32); bf16 mirror in LDS per chunk.
// ---------------------------------------------------------------------------
__global__ __launch_bounds__(512, 2) void ttt_chunk(
    const unsigned short* __restrict__ K,
    const unsigned short* __restrict__ V,
    const unsigned short* __restrict__ Q,
    const unsigned short* __restrict__ Kt,
    const unsigned short* __restrict__ Linv,
    const unsigned short* __restrict__ Mp,
    const float* __restrict__ W0,
    const float* __restrict__ b0,
    float* __restrict__ out)
{
    __shared__ unsigned short Wb[32][1032];
    __shared__ unsigned short Ut[32][72];
    __shared__ unsigned short Gt[32][72];
    __shared__ float bb[32];

    const int tid = threadIdx.x;
    const int lane = tid & 63;
    const int w = tid >> 6;
    const int m = w & 1;
    const int n4 = w >> 1;
    const int lm = lane & 15;
    const int quad = lane >> 4;
    const int batch = blockIdx.x & 7;
    const int r0 = (blockIdx.x >> 3) * 32;
    const int myrow = m * 16 + lm;

    float4v acc_w[16];
#pragma unroll
    for (int i = 0; i < 16; ++i) {
        int nt = n4 + 4 * i;
#pragma unroll
        for (int r = 0; r < 4; ++r)
            acc_w[i][r] = W0[(size_t)(r0 + m * 16 + quad * 4 + r) * 1024 + nt * 16 + lm];
    }
    if (tid < 32) bb[tid] = b0[r0 + tid];

    const size_t tokBase = (size_t)batch * 2048;
    const float sc = 2.0f / 1024.0f;

    for (int c = 0; c < 32; ++c) {
        // (a) dump fp32 W regs -> bf16 LDS mirror
#pragma unroll
        for (int i = 0; i < 16; ++i) {
            int nt = n4 + 4 * i;
#pragma unroll
            for (int r = 0; r < 4; ++r)
                Wb[m * 16 + quad * 4 + r][nt * 16 + lm] = f2bf(acc_w[i][r]);
        }
        __syncthreads();

        // (b) Ut = (2/d)(W K^T + b - V)   [32 rows x 64 tokens]
        const size_t tokN = tokBase + c * 64 + n4 * 16 + lm;
        float4v acc = (float4v){0,0,0,0};
#pragma unroll
        for (int ks = 0; ks < 32; ++ks) {
            short8 af = *(const short8*)&Wb[myrow][ks * 32 + quad * 8];
            short8 bf = *(const short8*)(K + tokN * 1024 + ks * 32 + quad * 8);
            acc = __builtin_amdgcn_mfma_f32_16x16x32_bf16(af, bf, acc, 0, 0, 0);
        }
        float4v bval = *(const float4v*)&bb[m * 16 + quad * 4];
        ushort4v vv = *(const ushort4v*)(V + tokN * 1024 + r0 + m * 16 + quad * 4);
#pragma unroll
        for (int r = 0; r < 4; ++r) {
            float uval = sc * (acc[r] + bval[r] - bf2f(vv[r]));
            Ut[m * 16 + quad * 4 + r][n4 * 16 + lm] = f2bf(uval);
        }
        __syncthreads();

        // (c) Gt = Ut * Linv^T-contraction   [32 x 64]
        const size_t lbase = ((size_t)(batch * 32 + c)) * 4096 + (size_t)(n4 * 16 + lm) * 64;
        acc = (float4v){0,0,0,0};
#pragma unroll
        for (int ks = 0; ks < 2; ++ks) {
            short8 af = *(const short8*)&Ut[myrow][ks * 32 + quad * 8];
            short8 bf = *(const short8*)(Linv + lbase + ks * 32 + quad * 8);
            acc = __builtin_amdgcn_mfma_f32_16x16x32_bf16(af, bf, acc, 0, 0, 0);
        }
#pragma unroll
        for (int r = 0; r < 4; ++r)
            Gt[m * 16 + quad * 4 + r][n4 * 16 + lm] = f2bf(acc[r]);
        __syncthreads();

        // (d) Ot = W Q^T + b + Gt Mp^T-contraction ; store
        short8 ag0 = *(const short8*)&Gt[myrow][quad * 8];
        short8 ag1 = *(const short8*)&Gt[myrow][32 + quad * 8];
        acc = (float4v){0,0,0,0};
#pragma unroll
        for (int ks = 0; ks < 32; ++ks) {
            short8 af = *(const short8*)&Wb[myrow][ks * 32 + quad * 8];
            short8 bf = *(const short8*)(Q + tokN * 1024 + ks * 32 + quad * 8);
            acc = __builtin_amdgcn_mfma_f32_16x16x32_bf16(af, bf, acc, 0, 0, 0);
        }
        {
            short8 bm0 = *(const short8*)(Mp + lbase + quad * 8);
            short8 bm1 = *(const short8*)(Mp + lbase + 32 + quad * 8);
            acc = __builtin_amdgcn_mfma_f32_16x16x32_bf16(ag0, bm0, acc, 0, 0, 0);
            acc = __builtin_amdgcn_mfma_f32_16x16x32_bf16(ag1, bm1, acc, 0, 0, 0);
        }
        float4v ov;
#pragma unroll
        for (int r = 0; r < 4; ++r) ov[r] = acc[r] + bval[r];
        *(float4v*)(out + tokN * 1024 + r0 + m * 16 + quad * 4) = ov;

        // (e) W += Gt * Kt-contraction  (Kt pre-scaled by -LR)
#pragma unroll
        for (int i = 0; i < 16; ++i) {
            int nt = n4 + 4 * i;
            const unsigned short* kp = Kt + (size_t)batch * 2097152 +
                                       (size_t)(nt * 16 + lm) * 2048 + c * 64;
            short8 kb0 = *(const short8*)(kp + quad * 8);
            short8 kb1 = *(const short8*)(kp + 32 + quad * 8);
            acc_w[i] = __builtin_amdgcn_mfma_f32_16x16x32_bf16(ag0, kb0, acc_w[i], 0, 0, 0);
            acc_w[i] = __builtin_amdgcn_mfma_f32_16x16x32_bf16(ag1, kb1, acc_w[i], 0, 0, 0);
        }

        // (f) bias update
        if (tid < 32) {
            float s = 0.f;
#pragma unroll 8
            for (int t = 0; t < 64; ++t) s += bf2f(Gt[tid][t]);
            bb[tid] -= LR * s;
        }
        __syncthreads();
    }
}

// ---------------------------------------------------------------------------
extern "C" void kernel_launch(void* const* d_in, const int* in_sizes, int n_in,
                              void* d_out, int out_size, void* d_ws, size_t ws_size,
                              hipStream_t stream) {
    (void)in_sizes; (void)n_in; (void)out_size; (void)ws_size;
    const float* in_seq = (const float*)d_in[0];
    const float* thK    = (const float*)d_in[1];
    const float* thV    = (const float*)d_in[2];
    const float* thQ    = (const float*)d_in[3];
    const float* W0     = (const float*)d_in[4];
    const float* b0     = (const float*)d_in[5];
    float* out = (float*)d_out;

    unsigned short* ws = (unsigned short*)d_ws;
    unsigned short* Kp   = ws;                                  // 32 MB
    unsigned short* Vp   = ws + (size_t)16384 * 1024;           // 32 MB
    unsigned short* Qp   = ws + (size_t)2 * 16384 * 1024;       // 32 MB
    unsigned short* Ktp  = ws + (size_t)3 * 16384 * 1024;       // 32 MB
    unsigned short* Linv = ws + (size_t)4 * 16384 * 1024;       // 2 MB
    unsigned short* Mpp  = Linv + (size_t)8 * 32 * 4096;        // 2 MB

    dim3 g1(16384 / 64, 1024 / 64, 3);
    proj_gemm<<<g1, 256, 0, stream>>>(in_seq, thK, thV, thQ, Kp, Ktp);

    precomp<<<256, 256, 0, stream>>>(Kp, Qp, Linv, Mpp);

    ttt_chunk<<<256, 512, 0, stream>>>(Kp, Vp, Qp, Ktp, Linv, Mpp, W0, b0, out);
}

// Round 4
// 1242.602 us; speedup vs baseline: 2.9407x; 1.1220x over previous
//
#include <hip/hip_runtime.h>
#include <hip/hip_bf16.h>

#define LR 0.01f

typedef __attribute__((ext_vector_type(8))) short short8;
typedef __attribute__((ext_vector_type(4))) float float4v;
typedef __attribute__((ext_vector_type(4))) unsigned short ushort4v;

static __device__ __forceinline__ unsigned short f2bf(float x) {
    union { float f; unsigned u; } un; un.f = x;
    unsigned r = un.u + 0x7fffu + ((un.u >> 16) & 1u);   // RNE
    return (unsigned short)(r >> 16);
}
static __device__ __forceinline__ float bf2f(unsigned short x) {
    union { float f; unsigned u; } un; un.u = ((unsigned)x) << 16;
    return un.f;
}

// ---------------------------------------------------------------------------
// Phase 1: K/V/Q projections, bf16 out. Also writes Kt = -LR * K^T  [b][j][s].
// ---------------------------------------------------------------------------
__global__ __launch_bounds__(256) void proj_gemm(
    const float* __restrict__ A,
    const float* __restrict__ T0, const float* __restrict__ T1,
    const float* __restrict__ T2,
    unsigned short* __restrict__ out,
    unsigned short* __restrict__ ktw)
{
    const float* Bt = (blockIdx.z == 0) ? T0 : (blockIdx.z == 1 ? T1 : T2);
    unsigned short* C = out + (size_t)blockIdx.z * (size_t)16384 * 1024;

    __shared__ unsigned short As[64][40];
    __shared__ unsigned short Bs[64][40];

    const int tid  = threadIdx.x;
    const int lane = tid & 63;
    const int wave = tid >> 6;
    const int m0 = blockIdx.x * 64;
    const int n0 = blockIdx.y * 64;
    const int srow = tid >> 2;
    const int sseg = (tid & 3) * 8;
    const int mrow = lane & 15;
    const int quad = lane >> 4;

    float4v acc[4];
#pragma unroll
    for (int i = 0; i < 4; ++i) acc[i] = (float4v){0.f, 0.f, 0.f, 0.f};

    const float* apBase = A  + (size_t)(m0 + srow) * 1024 + sseg;
    const float* bpBase = Bt + (size_t)(n0 + srow) * 1024 + sseg;

    for (int kt = 0; kt < 1024; kt += 32) {
        const float4v* ap4 = (const float4v*)(apBase + kt);
        const float4v* bp4 = (const float4v*)(bpBase + kt);
        float4v av0 = ap4[0], av1 = ap4[1];
        float4v bv0 = bp4[0], bv1 = bp4[1];

        __syncthreads();
        short8 apk, bpk;
#pragma unroll
        for (int i = 0; i < 4; ++i) {
            apk[i]     = (short)f2bf(av0[i]);
            apk[i + 4] = (short)f2bf(av1[i]);
            bpk[i]     = (short)f2bf(bv0[i]);
            bpk[i + 4] = (short)f2bf(bv1[i]);
        }
        *(short8*)&As[srow][sseg] = apk;
        *(short8*)&Bs[srow][sseg] = bpk;
        __syncthreads();

        short8 af = *(const short8*)&As[16 * wave + mrow][quad * 8];
#pragma unroll
        for (int nb = 0; nb < 4; ++nb) {
            short8 bfr = *(const short8*)&Bs[16 * nb + mrow][quad * 8];
            acc[nb] = __builtin_amdgcn_mfma_f32_16x16x32_bf16(af, bfr, acc[nb], 0, 0, 0);
        }
    }

    const int batch = m0 >> 11;
    const int s0    = m0 & 2047;
#pragma unroll
    for (int nb = 0; nb < 4; ++nb) {
#pragma unroll
        for (int r = 0; r < 4; ++r) {
            int tl = 16 * wave + quad * 4 + r;     // token-local
            int jl = 16 * nb + mrow;               // dim-local
            C[(size_t)(m0 + tl) * 1024 + (n0 + jl)] = f2bf(acc[nb][r]);
            if (blockIdx.z == 0) {
                ktw[(size_t)batch * 2097152 + (size_t)(n0 + jl) * 2048 + s0 + tl] =
                    f2bf(-LR * acc[nb][r]);
            }
        }
    }
}

// ---------------------------------------------------------------------------
// Phase 2: per (batch, chunk): Linv = (I+L)^-1 via Neumann (I - L + L^2 - L^3),
// Mp = -LR * tril(Q K^T + 1). L = (2LR/d)*strict_tril(K K^T + 1).
// ---------------------------------------------------------------------------
__global__ __launch_bounds__(256) void precomp(
    const unsigned short* __restrict__ K,
    const unsigned short* __restrict__ Q,
    unsigned short* __restrict__ LinvG,
    unsigned short* __restrict__ MpG)
{
    __shared__ float Skk[64][68];
    __shared__ float Sqk[64][68];
    __shared__ unsigned short Lb[64][72];
    __shared__ unsigned short Xa[64][72];

    const int tid = threadIdx.x;
    const int lane = tid & 63;
    const int w = tid >> 6;
    const int lm = lane & 15;
    const int quad = lane >> 4;
    const int batch = blockIdx.x >> 5;
    const int c = blockIdx.x & 31;
    const size_t blk = (size_t)batch * 32 + c;

    float4v kk[4], qk[4];
#pragma unroll
    for (int i = 0; i < 4; ++i) { kk[i] = (float4v){0,0,0,0}; qk[i] = (float4v){0,0,0,0}; }

    const size_t tokA = (size_t)batch * 2048 + c * 64 + w * 16 + lm;
#pragma unroll 4
    for (int ks = 0; ks < 32; ++ks) {
        short8 aK = *(const short8*)(K + tokA * 1024 + ks * 32 + quad * 8);
        short8 aQ = *(const short8*)(Q + tokA * 1024 + ks * 32 + quad * 8);
#pragma unroll
        for (int nb = 0; nb < 4; ++nb) {
            size_t tokB = (size_t)batch * 2048 + c * 64 + nb * 16 + lm;
            short8 bK = *(const short8*)(K + tokB * 1024 + ks * 32 + quad * 8);
            kk[nb] = __builtin_amdgcn_mfma_f32_16x16x32_bf16(aK, bK, kk[nb], 0, 0, 0);
            qk[nb] = __builtin_amdgcn_mfma_f32_16x16x32_bf16(aQ, bK, qk[nb], 0, 0, 0);
        }
    }
#pragma unroll
    for (int nb = 0; nb < 4; ++nb)
#pragma unroll
        for (int r = 0; r < 4; ++r) {
            Skk[w * 16 + quad * 4 + r][nb * 16 + lm] = kk[nb][r];
            Sqk[w * 16 + quad * 4 + r][nb * 16 + lm] = qk[nb][r];
        }
    __syncthreads();

    const float c1 = 2.0f * LR / 1024.0f;
#pragma unroll
    for (int e = 0; e < 16; ++e) {
        int idx = tid * 16 + e;
        int t = idx >> 6, i = idx & 63;
        float a = (i < t) ? c1 * (Skk[t][i] + 1.0f) : 0.0f;
        Lb[t][i] = f2bf(a);
        Xa[i][t] = f2bf(((i == t) ? 1.0f : 0.0f) - a);
        float mq = (i <= t) ? -LR * (Sqk[t][i] + 1.0f) : 0.0f;
        MpG[blk * 4096 + (size_t)t * 64 + i] = f2bf(mq);
    }
    __syncthreads();

    short8 afL0 = *(const short8*)&Lb[w * 16 + lm][quad * 8];
    short8 afL1 = *(const short8*)&Lb[w * 16 + lm][32 + quad * 8];
    float4v p[4];
#pragma unroll
    for (int nb = 0; nb < 4; ++nb) {
        p[nb] = (float4v){0,0,0,0};
        short8 b0f = *(const short8*)&Xa[nb * 16 + lm][quad * 8];
        short8 b1f = *(const short8*)&Xa[nb * 16 + lm][32 + quad * 8];
        p[nb] = __builtin_amdgcn_mfma_f32_16x16x32_bf16(afL0, b0f, p[nb], 0, 0, 0);
        p[nb] = __builtin_amdgcn_mfma_f32_16x16x32_bf16(afL1, b1f, p[nb], 0, 0, 0);
    }
    __syncthreads();
#pragma unroll
    for (int nb = 0; nb < 4; ++nb)
#pragma unroll
        for (int r = 0; r < 4; ++r) {
            int ii = nb * 16 + lm, tt = w * 16 + quad * 4 + r;
            Xa[ii][tt] = f2bf(((ii == tt) ? 1.0f : 0.0f) - p[nb][r]);
        }
    __syncthreads();

#pragma unroll
    for (int nb = 0; nb < 4; ++nb) {
        p[nb] = (float4v){0,0,0,0};
        short8 b0f = *(const short8*)&Xa[nb * 16 + lm][quad * 8];
        short8 b1f = *(const short8*)&Xa[nb * 16 + lm][32 + quad * 8];
        p[nb] = __builtin_amdgcn_mfma_f32_16x16x32_bf16(afL0, b0f, p[nb], 0, 0, 0);
        p[nb] = __builtin_amdgcn_mfma_f32_16x16x32_bf16(afL1, b1f, p[nb], 0, 0, 0);
    }
#pragma unroll
    for (int nb = 0; nb < 4; ++nb)
#pragma unroll
        for (int r = 0; r < 4; ++r) {
            int ii = nb * 16 + lm, tt = w * 16 + quad * 4 + r;
            LinvG[blk * 4096 + (size_t)tt * 64 + ii] =
                f2bf(((ii == tt) ? 1.0f : 0.0f) - p[nb][r]);
        }
}

// ---------------------------------------------------------------------------
// Phase 3: chunked TTT. 512 blocks = 8 batches x 64 row-slabs (16 rows each),
// 256 threads (4 waves). Round-2-verified fragment roles throughout:
//   acc_w[i][r] = W[row = quad*4+r][col = (w+4i)*16 + lm]  (fp32, MFMA C/D)
// O = W Q^T fused into step (b) (shared A-frag, independent MFMA chain).
// ---------------------------------------------------------------------------
__global__ __launch_bounds__(256) void ttt_chunk(
    const unsigned short* __restrict__ K,
    const unsigned short* __restrict__ V,
    const unsigned short* __restrict__ Q,
    const unsigned short* __restrict__ Kt,
    const unsigned short* __restrict__ Linv,
    const unsigned short* __restrict__ Mp,
    const float* __restrict__ W0,
    const float* __restrict__ b0,
    float* __restrict__ out)
{
    __shared__ unsigned short Wb[16][1032];
    __shared__ unsigned short Ut[16][72];
    __shared__ unsigned short Gt[16][72];
    __shared__ float bb[16];

    const int tid  = threadIdx.x;
    const int lane = tid & 63;
    const int w    = tid >> 6;          // wave 0..3 = token-group for U/O/G
    const int lm   = lane & 15;
    const int quad = lane >> 4;
    const int batch = blockIdx.x & 7;
    const int r0    = (blockIdx.x >> 3) * 16;   // row-slab base

    // W init, round-2 acc layout (C/D rows = W rows)
    float4v acc_w[16];
#pragma unroll
    for (int i = 0; i < 16; ++i) {
        int nt = w + 4 * i;
#pragma unroll
        for (int r = 0; r < 4; ++r)
            acc_w[i][r] = W0[(size_t)(r0 + quad * 4 + r) * 1024 + nt * 16 + lm];
    }
    if (tid < 16) bb[tid] = b0[r0 + tid];

    const size_t tokBase = (size_t)batch * 2048;
    const unsigned short* KtB = Kt + (size_t)batch * 2097152;
    const float sc = 2.0f / 1024.0f;

    for (int c = 0; c < 32; ++c) {
        // (a) dump fp32 W regs -> bf16 LDS mirror (scalar, round-2 pattern)
#pragma unroll
        for (int i = 0; i < 16; ++i) {
            int nt = w + 4 * i;
#pragma unroll
            for (int r = 0; r < 4; ++r)
                Wb[quad * 4 + r][nt * 16 + lm] = f2bf(acc_w[i][r]);
        }
        __syncthreads();

        // (b) U = (2/d)(W K^T + b - V)  AND  O_acc = W Q^T   (shared af)
        const size_t tok = tokBase + c * 64 + w * 16 + lm;   // this lane's token
        float4v accU = (float4v){0,0,0,0};
        float4v accO = (float4v){0,0,0,0};
#pragma unroll 4
        for (int ks = 0; ks < 32; ++ks) {
            short8 af = *(const short8*)&Wb[lm][ks * 32 + quad * 8];
            short8 kf = *(const short8*)(K + tok * 1024 + ks * 32 + quad * 8);
            short8 qf = *(const short8*)(Q + tok * 1024 + ks * 32 + quad * 8);
            accU = __builtin_amdgcn_mfma_f32_16x16x32_bf16(af, kf, accU, 0, 0, 0);
            accO = __builtin_amdgcn_mfma_f32_16x16x32_bf16(af, qf, accO, 0, 0, 0);
        }
        float4v bval = *(const float4v*)&bb[quad * 4];
        ushort4v vv = *(const ushort4v*)(V + tok * 1024 + r0 + quad * 4);
#pragma unroll
        for (int r = 0; r < 4; ++r) {
            float uval = sc * (accU[r] + bval[r] - bf2f(vv[r]));
            Ut[quad * 4 + r][w * 16 + lm] = f2bf(uval);
        }
        __syncthreads();

        // (c) G^T = Ut . Linv^T-contraction   [16 rows x 64 tokens]
        const size_t lbase = ((size_t)(batch * 32 + c)) * 4096 + (size_t)(w * 16 + lm) * 64;
        float4v accG = (float4v){0,0,0,0};
        {
            short8 a0 = *(const short8*)&Ut[lm][quad * 8];
            short8 a1 = *(const short8*)&Ut[lm][32 + quad * 8];
            short8 l0 = *(const short8*)(Linv + lbase + quad * 8);
            short8 l1 = *(const short8*)(Linv + lbase + 32 + quad * 8);
            accG = __builtin_amdgcn_mfma_f32_16x16x32_bf16(a0, l0, accG, 0, 0, 0);
            accG = __builtin_amdgcn_mfma_f32_16x16x32_bf16(a1, l1, accG, 0, 0, 0);
        }
#pragma unroll
        for (int r = 0; r < 4; ++r)
            Gt[quad * 4 + r][w * 16 + lm] = f2bf(accG[r]);
        __syncthreads();

        // (d) O += Gt . Mp-contraction + b ; store
        short8 ag0 = *(const short8*)&Gt[lm][quad * 8];
        short8 ag1 = *(const short8*)&Gt[lm][32 + quad * 8];
        {
            short8 m0f = *(const short8*)(Mp + lbase + quad * 8);
            short8 m1f = *(const short8*)(Mp + lbase + 32 + quad * 8);
            accO = __builtin_amdgcn_mfma_f32_16x16x32_bf16(ag0, m0f, accO, 0, 0, 0);
            accO = __builtin_amdgcn_mfma_f32_16x16x32_bf16(ag1, m1f, accO, 0, 0, 0);
        }
        float4v ov;
#pragma unroll
        for (int r = 0; r < 4; ++r) ov[r] = accO[r] + bval[r];
        *(float4v*)(out + tok * 1024 + r0 + quad * 4) = ov;

        // (e) W += Gt . Kt-contraction  (round-2 operand order: A=Gt, B=Kt)
#pragma unroll
        for (int i = 0; i < 16; ++i) {
            int nt = w + 4 * i;
            const unsigned short* kp = KtB + (size_t)(nt * 16 + lm) * 2048 + c * 64;
            short8 kb0 = *(const short8*)(kp + quad * 8);
            short8 kb1 = *(const short8*)(kp + 32 + quad * 8);
            acc_w[i] = __builtin_amdgcn_mfma_f32_16x16x32_bf16(ag0, kb0, acc_w[i], 0, 0, 0);
            acc_w[i] = __builtin_amdgcn_mfma_f32_16x16x32_bf16(ag1, kb1, acc_w[i], 0, 0, 0);
        }

        // (f) bias update
        if (tid < 16) {
            float s = 0.f;
#pragma unroll 8
            for (int t = 0; t < 64; ++t) s += bf2f(Gt[tid][t]);
            bb[tid] -= LR * s;
        }
        __syncthreads();
    }
}

// ---------------------------------------------------------------------------
extern "C" void kernel_launch(void* const* d_in, const int* in_sizes, int n_in,
                              void* d_out, int out_size, void* d_ws, size_t ws_size,
                              hipStream_t stream) {
    (void)in_sizes; (void)n_in; (void)out_size; (void)ws_size;
    const float* in_seq = (const float*)d_in[0];
    const float* thK    = (const float*)d_in[1];
    const float* thV    = (const float*)d_in[2];
    const float* thQ    = (const float*)d_in[3];
    const float* W0     = (const float*)d_in[4];
    const float* b0     = (const float*)d_in[5];
    float* out = (float*)d_out;

    unsigned short* ws = (unsigned short*)d_ws;
    unsigned short* Kp   = ws;                                  // 32 MB
    unsigned short* Vp   = ws + (size_t)16384 * 1024;           // 32 MB
    unsigned short* Qp   = ws + (size_t)2 * 16384 * 1024;       // 32 MB
    unsigned short* Ktp  = ws + (size_t)3 * 16384 * 1024;       // 32 MB
    unsigned short* Linv = ws + (size_t)4 * 16384 * 1024;       // 2 MB
    unsigned short* Mpp  = Linv + (size_t)8 * 32 * 4096;        // 2 MB

    dim3 g1(16384 / 64, 1024 / 64, 3);
    proj_gemm<<<g1, 256, 0, stream>>>(in_seq, thK, thV, thQ, Kp, Ktp);

    precomp<<<256, 256, 0, stream>>>(Kp, Qp, Linv, Mpp);

    ttt_chunk<<<512, 256, 0, stream>>>(Kp, Vp, Qp, Ktp, Linv, Mpp, W0, b0, out);
}